// Round 6
// baseline (110.295 us; speedup 1.0000x reference)
//
#include <hip/hip_runtime.h>
#include <math.h>

#define Dd 96
#define Nn 48
#define LD 97
#define PTS 98   // even stride: keeps float2 (8 B) LDS loads aligned

// Fast full-precision f64 reciprocal: v_rcp_f64 + 2 Newton steps (<=1 ulp).
__device__ __forceinline__ double frcp(double x) {
    double r = __builtin_amdgcn_rcp(x);
    r = fma(fma(-x, r, 1.0), r, r);
    r = fma(fma(-x, r, 1.0), r, r);
    return r;
}

// One block per particle k (P f32; R16-verified math).
// R25: R24's register-resident elimination, SPILL-FREE.
//  - R24 post-mortem: VGPR capped at 64 -> Bd[6][6] spilled to scratch
//    (WRITE_SIZE 19KB->787KB), scratch latency on the per-step critical
//    path. Fix: amdgpu_waves_per_eu(4,4) pins the 128-VGPR budget (16-wave
//    block = 4 waves/EU exactly), plus register diet in prefactor:
//    guards interleaved into the LU (no pivs[]), rp stored into Bd diag,
//    sequential slot solves. Peak ~120 VGPR.
//  - tail: dump + barriered remainder replaced by in-register mini-LU
//    (final rsz<=6 block lives wholly in wave jend/6's registers).
//  - guards/emission semantics identical to R16; merged prod epilogue kept.
__attribute__((amdgpu_waves_per_eu(4, 4)))
__global__ __launch_bounds__(1024) void slater_kernel(const float* __restrict__ P,
                                                      const int* __restrict__ occ,
                                                      float* __restrict__ out,
                                                      unsigned* __restrict__ cnt) {
    __shared__ double As[Dd * LD];      // 74,496 B (build + initial reg load)
    __shared__ double Sbuf[2][6][Dd];   // 9,216 B: S rows for the step
    __shared__ double aBuf[2][Dd][8];   // 12,288 B: panel cols per row (64B rows)
    __shared__ double ev[2][6];
    __shared__ int    evmask[2], sdead[2];
    __shared__ double evm[6];           // mini-LU emissions
    __shared__ int    evmmask;
    __shared__ double gs_runprod;       // guard-state handoff
    __shared__ int    gs_dead;
    __shared__ unsigned char flag[Dd];
    float* PT = (float*)As;             // scratch alias; PT reads end before As writes

    const int tid  = threadIdx.x;
    const int k    = blockIdx.x;
    const int n    = Dd - Nn + k + 1;   // xmax
    const int lane = tid & 63;
    const int wave = tid >> 6;          // 0..15
    const int xmin = (k == 0) ? 0 : occ[k - 1] + 1;

    if (tid < Dd) flag[tid] = 0;
    __syncthreads();
    if (tid < k) flag[occ[tid]] = 1;
    for (int e = tid; e < Dd * Nn; e += 1024) {      // PT[t][c] = P[c][t]
        int c = e / Nn, t = e - (e / Nn) * Nn;
        PT[t * PTS + c] = P[e];
    }
    __syncthreads();

    // A = I*(1-flag) - P P^T is SYMMETRIC: upper-tri 2x2 tiles (1176), mirror
    // writes for the lower half. 1024 threads -> 2 partial iterations.
    double Areg[8]; int trs[2], tcs[2];
#pragma unroll
    for (int it = 0; it < 2; ++it) {
        int tau = tid + 1024 * it;
        double s00 = 0.0, s01 = 0.0, s10 = 0.0, s11 = 0.0;
        int tr = 0, tc = 0;
        if (tau < 1176) {
            tr = (int)((97.0 - sqrt(9409.0 - 8.0 * (double)tau)) * 0.5);
            while ((tr * (97 - tr)) / 2 > tau) --tr;            // off(tr) <= tau
            while (((tr + 1) * (96 - tr)) / 2 <= tau) ++tr;     // off(tr+1) > tau
            tc = tr + (tau - (tr * (97 - tr)) / 2);
            int r0 = 2 * tr, c0 = 2 * tc;
            if (r0 < n && c0 < n) {
                for (int t = 0; t < Nn; ++t) {
                    const float* row = PT + t * PTS;
                    float2 pr = *(const float2*)(row + r0);
                    float2 pc = *(const float2*)(row + c0);
                    s00 -= (double)pr.x * (double)pc.x; s01 -= (double)pr.x * (double)pc.y;
                    s10 -= (double)pr.y * (double)pc.x; s11 -= (double)pr.y * (double)pc.y;
                }
            }
        }
        trs[it] = tr; tcs[it] = tc;
        Areg[it * 4 + 0] = s00; Areg[it * 4 + 1] = s01;
        Areg[it * 4 + 2] = s10; Areg[it * 4 + 3] = s11;
    }
    __syncthreads();                    // all PT reads done before As overwrite
#pragma unroll
    for (int it = 0; it < 2; ++it) {
        int tau = tid + 1024 * it;
        if (tau < 1176) {
            int tr = trs[it], tc = tcs[it];
            int r0 = 2 * tr, c0 = 2 * tc;
            if (r0 < n && c0 < n) {
                bool r1 = (r0 + 1 < n), c1 = (c0 + 1 < n);
                double d0 = flag[r0] ? 0.0 : 1.0;
                double d1 = flag[r0 + 1] ? 0.0 : 1.0;
                As[r0 * LD + c0] = Areg[it * 4 + 0] + ((r0 == c0) ? d0 : 0.0);
                if (c1)       As[r0 * LD + c0 + 1]       = Areg[it * 4 + 1];
                if (r1)       As[(r0 + 1) * LD + c0]     = Areg[it * 4 + 2];
                if (r1 && c1) As[(r0 + 1) * LD + c0 + 1] = Areg[it * 4 + 3] + ((r0 == c0) ? d1 : 0.0);
                if (tr != tc) {  // mirror (transpose) write
                    As[c0 * LD + r0] = Areg[it * 4 + 0];
                    if (c1)       As[(c0 + 1) * LD + r0]     = Areg[it * 4 + 1];
                    if (r1)       As[c0 * LD + r0 + 1]       = Areg[it * 4 + 2];
                    if (r1 && c1) As[(c0 + 1) * LD + r0 + 1] = Areg[it * 4 + 3];
                }
            }
        }
    }
    __syncthreads();

    double myprob = 0.0;
    double rr[6][2];                    // my 6 rows x my 2 cols

    // Owner-wave routine: gather panel B via intra-wave shuffles; 6x6 LU with
    // the guard chain INTERLEAVED (no pivs array; rp overwrites diag);
    // S = B^-1 R for my 2 col slots, sequentially. Guards redundant across
    // lanes (scalar regs); lane0 writes ev/evmask/sdead/gs.
    auto prefactor = [&](int jb, int p, double grun, int gdead) {
        double Bd[6][6];
#pragma unroll
        for (int u = 0; u < 6; ++u)
#pragma unroll
            for (int r = 0; r < 6; ++r)
                Bd[u][r] = __shfl((r & 1) ? rr[u][1] : rr[u][0], (jb + r) >> 1, 64);
        int msk = 0;
#pragma unroll
        for (int cc = 0; cc < 6; ++cc) {
            double piv = Bd[cc][cc];
            double ap = fabs(piv);
            int jj = jb + cc;
            if (!gdead) {
                if (jj >= xmin) {
                    if (lane == 0) ev[p][cc] = grun * (1.0 - piv);  // emit BEFORE cut
                    msk |= (1 << cc);
                    double nr = grun * piv;
                    if (!(ap > 1e-7) || !(ap < 8.0) || !(fabs(nr) > 1e-8)) gdead = 1;
                    else grun = nr;
                } else {
                    if (!(ap > 1e-12) || !(ap < 8.0)) gdead = 1;
                }
            }
            double rp = frcp(piv);
            Bd[cc][cc] = rp;            // diag now holds reciprocal pivot
#pragma unroll
            for (int i = cc + 1; i < 6; ++i) {
                double m = Bd[i][cc] * rp;
                Bd[i][cc] = m;
#pragma unroll
                for (int r = cc + 1; r < 6; ++r) Bd[i][r] -= m * Bd[cc][r];
            }
        }
        if (lane == 0) {
            evmask[p] = msk; sdead[p] = gdead;
            gs_runprod = grun; gs_dead = gdead;
        }
        if (lane < 48) {
            const bool live = (2 * lane >= jb + 6);
#pragma unroll
            for (int sl = 0; sl < 2; ++sl) {
                double s0 = rr[0][sl];
                double s1 = rr[1][sl] - Bd[1][0] * s0;
                double s2 = rr[2][sl] - Bd[2][0] * s0 - Bd[2][1] * s1;
                double s3 = rr[3][sl] - Bd[3][0] * s0 - Bd[3][1] * s1 - Bd[3][2] * s2;
                double s4 = rr[4][sl] - Bd[4][0] * s0 - Bd[4][1] * s1 - Bd[4][2] * s2 - Bd[4][3] * s3;
                double s5 = rr[5][sl] - Bd[5][0] * s0 - Bd[5][1] * s1 - Bd[5][2] * s2 - Bd[5][3] * s3 - Bd[5][4] * s4;
                s5 = s5 * Bd[5][5];
                s4 = (s4 - Bd[4][5] * s5) * Bd[4][4];
                s3 = (s3 - Bd[3][4] * s4 - Bd[3][5] * s5) * Bd[3][3];
                s2 = (s2 - Bd[2][3] * s3 - Bd[2][4] * s4 - Bd[2][5] * s5) * Bd[2][2];
                s1 = (s1 - Bd[1][2] * s2 - Bd[1][3] * s3 - Bd[1][4] * s4 - Bd[1][5] * s5) * Bd[1][1];
                s0 = (s0 - Bd[0][1] * s1 - Bd[0][2] * s2 - Bd[0][3] * s3 - Bd[0][4] * s4 - Bd[0][5] * s5) * Bd[0][0];
                Sbuf[p][0][2 * lane + sl] = live ? s0 : 0.0;
                Sbuf[p][1][2 * lane + sl] = live ? s1 : 0.0;
                Sbuf[p][2][2 * lane + sl] = live ? s2 : 0.0;
                Sbuf[p][3][2 * lane + sl] = live ? s3 : 0.0;
                Sbuf[p][4][2 * lane + sl] = live ? s4 : 0.0;
                Sbuf[p][5][2 * lane + sl] = live ? s5 : 0.0;
            }
        }
    };

    // ---- load my rows into registers ----
#pragma unroll
    for (int u = 0; u < 6; ++u) {
        if (lane < 48) {
            rr[u][0] = As[(6 * wave + u) * LD + 2 * lane];
            rr[u][1] = As[(6 * wave + u) * LD + 2 * lane + 1];
        } else { rr[u][0] = 0.0; rr[u][1] = 0.0; }
    }
    // initial aBuf[0]: panel-0 cols (0..5) of all trailing rows (waves >= 1)
    if (wave >= 1 && lane < 3) {
#pragma unroll
        for (int u = 0; u < 6; ++u) {
            aBuf[0][6 * wave + u][2 * lane]     = rr[u][0];
            aBuf[0][6 * wave + u][2 * lane + 1] = rr[u][1];
        }
    }
    if (wave == 0) prefactor(0, 0, 1.0, 0);
    __syncthreads();

    // ---- rank-6 super-steps, matrix in registers ----
    int j = 0, s = 0;
    for (; j + 6 <= n - 1; j += 6, ++s) {
        const int par = s & 1;
        if (tid >= j && tid < j + 6) {           // emission (precomputed)
            int q = tid - j;
            if ((evmask[par] >> q) & 1) myprob = ev[par][q];
        }
        if (sdead[par]) break;
        const bool nexts = (j + 12 <= n - 1);    // next super-step exists

        if (wave >= s + 1) {
            if (lane < 48) {
                double S0[6], S1[6];
#pragma unroll
                for (int r = 0; r < 6; ++r) {
                    double2 sv = *(const double2*)&Sbuf[par][r][2 * lane];
                    S0[r] = sv.x; S1[r] = sv.y;
                }
#pragma unroll
                for (int u = 0; u < 6; ++u) {    // 72 register FMAs
                    const double* ab = &aBuf[par][6 * wave + u][0];
                    double2 q0 = *(const double2*)(ab + 0);
                    double2 q1 = *(const double2*)(ab + 2);
                    double2 q2 = *(const double2*)(ab + 4);
                    rr[u][0] -= q0.x * S0[0] + q0.y * S0[1] + q1.x * S0[2]
                              + q1.y * S0[3] + q2.x * S0[4] + q2.y * S0[5];
                    rr[u][1] -= q0.x * S1[0] + q0.y * S1[1] + q1.x * S1[2]
                              + q1.y * S1[3] + q2.x * S1[4] + q2.y * S1[5];
                }
                // publish next panel's a-cols (j+6..j+11) for rows that will
                // still be trailing at step s+1 (waves >= s+2)
                if (nexts && wave >= s + 2) {
                    int d = lane - 3 * (s + 1);
                    if (d >= 0 && d < 3) {
#pragma unroll
                        for (int u = 0; u < 6; ++u) {
                            aBuf[par ^ 1][6 * wave + u][2 * d]     = rr[u][0];
                            aBuf[par ^ 1][6 * wave + u][2 * d + 1] = rr[u][1];
                        }
                    }
                }
            }
            // owner of step s+1: everything intra-wave (B via shfl, R = regs)
            if (nexts && wave == s + 1)
                prefactor(j + 6, par ^ 1, gs_runprod, gs_dead);
        }
        __syncthreads();
    }

    // ---- in-register mini-LU for the final trailing block (rsz <= 6) ----
    // full = loop ran to completion (no dead-break). The block rows/cols
    // jend..n-1 live wholly in wave jend/6's registers.
    const int  jend = j;
    const bool full = (jend + 6 > n - 1);
    if (full && wave == (jend / 6)) {
        const int rsz = n - jend;                // 1..6
        double Bm[6][6];
#pragma unroll
        for (int u = 0; u < 6; ++u)
#pragma unroll
            for (int r = 0; r < 6; ++r)
                Bm[u][r] = __shfl((r & 1) ? rr[u][1] : rr[u][0], (jend + r) >> 1, 64);
        if (lane == 0) {
            double grun = gs_runprod; int gdead = gs_dead;   // covers cols < jend
            int msk = 0;
            double evs[6] = {0.0, 0.0, 0.0, 0.0, 0.0, 0.0};
            for (int q = 0; q < rsz - 1; ++q) {
                if (gdead) break;
                double piv = Bm[q][q];
                double ap = fabs(piv);
                int jj = jend + q;
                if (jj >= xmin) {
                    evs[q] = grun * (1.0 - piv); msk |= (1 << q);
                    double nr = grun * piv;
                    if (!(ap > 1e-7) || !(ap < 8.0) || !(fabs(nr) > 1e-8)) gdead = 1;
                    else grun = nr;
                } else {
                    if (!(ap > 1e-12) || !(ap < 8.0)) gdead = 1;
                }
                if (!gdead) {
                    double rp = frcp(piv);
                    for (int i = q + 1; i < rsz; ++i) {
                        double m = Bm[i][q] * rp;
                        for (int r = q + 1; r < rsz; ++r) Bm[i][r] -= m * Bm[q][r];
                    }
                }
            }
            if (!gdead) {                        // x = xmax-1: remaining mass
                evs[rsz - 1] = grun * (1.0 - Bm[rsz - 1][rsz - 1]);
                msk |= (1 << (rsz - 1));
            }
#pragma unroll
            for (int q = 0; q < 6; ++q) evm[q] = evs[q];
            evmmask = msk;
        }
    }
    __syncthreads();
    if (full && tid >= jend && tid < n) {
        int q = tid - jend;
        if ((evmmask >> q) & 1) myprob = evm[q];
    }

    if (tid < Dd) {
        double p = myprob;
        if (!isfinite(p)) p = 0.0;
        if (!(fabs(p) > 1e-15)) p = 0.0;   // reference's flush
        p = fmin(fmax(p, 0.0), 1.0);       // junk-proof projection
        out[k * Dd + tid] = (float)p;
    }

    // ---- merged prob_sample: last-arriving block does the product ----
    __threadfence();
    __syncthreads();
    if (wave == 0) {
        int old = 0;
        if (lane == 0)
            old = (int)__hip_atomic_fetch_add(cnt, 1u, __ATOMIC_ACQ_REL,
                                              __HIP_MEMORY_SCOPE_AGENT);
        old = __shfl(old, 0, 64);
        // Exactly one multiple of Nn in any Nn consecutive values -> exactly
        // one trigger per launch for ANY initial/poisoned counter value.
        if (((unsigned)old + 1u) % (unsigned)Nn == 0u) {
            __threadfence();            // acquire side
            double v = 1.0;
            if (lane < Nn) {
                float f = __hip_atomic_load(out + lane * Dd + occ[lane],
                                            __ATOMIC_RELAXED, __HIP_MEMORY_SCOPE_AGENT);
                v = (double)f;
            }
#pragma unroll
            for (int off = 32; off >= 1; off >>= 1)
                v *= __shfl_down(v, off, 64);
            if (lane == 0) {
                if (!isfinite(v)) v = 0.0;
                out[Nn * Dd] = (float)v;
            }
        }
    }
}

extern "C" void kernel_launch(void* const* d_in, const int* in_sizes, int n_in,
                              void* d_out, int out_size, void* d_ws, size_t ws_size,
                              hipStream_t stream) {
    const float* P = (const float*)d_in[0];      // 96x48 f32, row-major
    const int* occ = (const int*)d_in[1];        // 48 int32
    float* out = (float*)d_out;                  // 4609 f32

    slater_kernel<<<Nn, 1024, 0, stream>>>(P, occ, out, (unsigned*)d_ws);
}

// Round 7
// 97.735 us; speedup vs baseline: 1.1285x; 1.1285x over previous
//
#include <hip/hip_runtime.h>
#include <math.h>

#define Dd 96
#define Nn 48
#define LD 97
#define PTS 98   // even stride: keeps float2 (8 B) LDS loads aligned

// Fast full-precision f64 reciprocal: v_rcp_f64 + 2 Newton steps (<=1 ulp).
__device__ __forceinline__ double frcp(double x) {
    double r = __builtin_amdgcn_rcp(x);
    r = fma(fma(-x, r, 1.0), r, r);
    r = fma(fma(-x, r, 1.0), r, r);
    return r;
}

// Wave-uniform f64 broadcast from a lane (v_readlane -> SGPR pair, no LDS).
__device__ __forceinline__ double rdlane(double v, int srcLane) {
    union { double d; int i[2]; } u; u.d = v;
    int lo = __builtin_amdgcn_readlane(u.i[0], srcLane);
    int hi = __builtin_amdgcn_readlane(u.i[1], srcLane);
    union { int i[2]; double d; } w; w.i[0] = lo; w.i[1] = hi;
    return w.d;
}

// One block per particle k (P f32; R16-verified math).
// R26: register-resident elimination that FITS the 64-VGPR budget.
//  - R24/R25 post-mortem: Bd[6][6] per lane (36 dbl) spilled (WRITE_SIZE
//    ~700KB); two attempts to raise the budget failed. So: NO panel array.
//    Owner wave runs a shuffle-space Gauss-Jordan: rr already holds [B|R]
//    across lanes; per pivot, readlane-broadcast piv + factors, scale row,
//    fma rows -> rr becomes S = B^-1 R in place. ~12 temp regs.
//  - aBuf deleted: panel-col a-values ARE the wave's own frozen rr cols
//    (S=0 retirement) -> fetch via wave-uniform readlane (SGPR operand),
//    no LDS round-trip. Per-step LDS reads: 24 b128 -> 6 b128.
//  - mini-LU tail: same static shuffle-GJ with PREDICATED guards (no
//    runtime-indexed arrays -> no scratch).
//  - guards/emission semantics identical to R16; merged prod epilogue kept.
__global__ __launch_bounds__(1024, 1) void slater_kernel(const float* __restrict__ P,
                                                         const int* __restrict__ occ,
                                                         float* __restrict__ out,
                                                         unsigned* __restrict__ cnt) {
    __shared__ double As[Dd * LD];      // 74,496 B (build + initial reg load)
    __shared__ double Sbuf[2][6][Dd];   // 9,216 B: S rows for the step
    __shared__ double ev[2][6];
    __shared__ int    evmask[2], sdead[2];
    __shared__ double evm[6];           // mini-LU emissions
    __shared__ int    evmmask;
    __shared__ double gs_runprod;       // guard-state handoff
    __shared__ int    gs_dead;
    __shared__ unsigned char flag[Dd];
    float* PT = (float*)As;             // scratch alias; PT reads end before As writes

    const int tid  = threadIdx.x;
    const int k    = blockIdx.x;
    const int n    = Dd - Nn + k + 1;   // xmax
    const int lane = tid & 63;
    const int wave = tid >> 6;          // 0..15
    const int xmin = (k == 0) ? 0 : occ[k - 1] + 1;

    if (tid < Dd) flag[tid] = 0;
    __syncthreads();
    if (tid < k) flag[occ[tid]] = 1;
    for (int e = tid; e < Dd * Nn; e += 1024) {      // PT[t][c] = P[c][t]
        int c = e / Nn, t = e - (e / Nn) * Nn;
        PT[t * PTS + c] = P[e];
    }
    __syncthreads();

    // A = I*(1-flag) - P P^T is SYMMETRIC: upper-tri 2x2 tiles (1176), mirror
    // writes for the lower half. 1024 threads -> 2 partial iterations.
    double Areg[8]; int trs[2], tcs[2];
#pragma unroll
    for (int it = 0; it < 2; ++it) {
        int tau = tid + 1024 * it;
        double s00 = 0.0, s01 = 0.0, s10 = 0.0, s11 = 0.0;
        int tr = 0, tc = 0;
        if (tau < 1176) {
            tr = (int)((97.0 - sqrt(9409.0 - 8.0 * (double)tau)) * 0.5);
            while ((tr * (97 - tr)) / 2 > tau) --tr;            // off(tr) <= tau
            while (((tr + 1) * (96 - tr)) / 2 <= tau) ++tr;     // off(tr+1) > tau
            tc = tr + (tau - (tr * (97 - tr)) / 2);
            int r0 = 2 * tr, c0 = 2 * tc;
            if (r0 < n && c0 < n) {
                for (int t = 0; t < Nn; ++t) {
                    const float* row = PT + t * PTS;
                    float2 pr = *(const float2*)(row + r0);
                    float2 pc = *(const float2*)(row + c0);
                    s00 -= (double)pr.x * (double)pc.x; s01 -= (double)pr.x * (double)pc.y;
                    s10 -= (double)pr.y * (double)pc.x; s11 -= (double)pr.y * (double)pc.y;
                }
            }
        }
        trs[it] = tr; tcs[it] = tc;
        Areg[it * 4 + 0] = s00; Areg[it * 4 + 1] = s01;
        Areg[it * 4 + 2] = s10; Areg[it * 4 + 3] = s11;
    }
    __syncthreads();                    // all PT reads done before As overwrite
#pragma unroll
    for (int it = 0; it < 2; ++it) {
        int tau = tid + 1024 * it;
        if (tau < 1176) {
            int tr = trs[it], tc = tcs[it];
            int r0 = 2 * tr, c0 = 2 * tc;
            if (r0 < n && c0 < n) {
                bool r1 = (r0 + 1 < n), c1 = (c0 + 1 < n);
                double d0 = flag[r0] ? 0.0 : 1.0;
                double d1 = flag[r0 + 1] ? 0.0 : 1.0;
                As[r0 * LD + c0] = Areg[it * 4 + 0] + ((r0 == c0) ? d0 : 0.0);
                if (c1)       As[r0 * LD + c0 + 1]       = Areg[it * 4 + 1];
                if (r1)       As[(r0 + 1) * LD + c0]     = Areg[it * 4 + 2];
                if (r1 && c1) As[(r0 + 1) * LD + c0 + 1] = Areg[it * 4 + 3] + ((r0 == c0) ? d1 : 0.0);
                if (tr != tc) {  // mirror (transpose) write
                    As[c0 * LD + r0] = Areg[it * 4 + 0];
                    if (c1)       As[(c0 + 1) * LD + r0]     = Areg[it * 4 + 1];
                    if (r1)       As[c0 * LD + r0 + 1]       = Areg[it * 4 + 2];
                    if (r1 && c1) As[(c0 + 1) * LD + r0 + 1] = Areg[it * 4 + 3];
                }
            }
        }
    }
    __syncthreads();

    double myprob = 0.0;
    double rr[6][2];                    // my 6 rows x my 2 cols

    // Owner-wave shuffle-GJ: transform rr = [B|R] into S = B^-1 R in place.
    // jb is always even (multiple of 6) -> slot index cc&1 is compile-time.
    // Guards run redundantly on all lanes (wave-uniform via readlane);
    // lane0 writes ev/evmask/sdead/gs. Publishes Sbuf[p] (0 for cols<jb+6).
    auto prefactor = [&](int jb, int p, double grun, int gdead) {
        const int jbH = jb >> 1;
        int msk = 0;
#pragma unroll
        for (int cc = 0; cc < 6; ++cc) {
            const int src = jbH + (cc >> 1);
            double piv = rdlane(rr[cc][cc & 1], src);
            if (!gdead) {
                double ap = fabs(piv);
                int jj = jb + cc;
                if (jj >= xmin) {
                    if (lane == 0) ev[p][cc] = grun * (1.0 - piv);  // emit BEFORE cut
                    msk |= (1 << cc);
                    double nr = grun * piv;
                    if (!(ap > 1e-7) || !(ap < 8.0) || !(fabs(nr) > 1e-8)) gdead = 1;
                    else grun = nr;
                } else {
                    if (!(ap > 1e-12) || !(ap < 8.0)) gdead = 1;
                }
            }
            double rp = frcp(piv);
            rr[cc][0] *= rp; rr[cc][1] *= rp;
#pragma unroll
            for (int i = 0; i < 6; ++i) {
                if (i == cc) continue;
                double f = rdlane(rr[i][cc & 1], src);
                rr[i][0] -= f * rr[cc][0];
                rr[i][1] -= f * rr[cc][1];
            }
        }
        if (lane == 0) {
            evmask[p] = msk; sdead[p] = gdead;
            gs_runprod = grun; gs_dead = gdead;
        }
        if (lane < 48) {
            const bool live = (2 * lane >= jb + 6);
#pragma unroll
            for (int r = 0; r < 6; ++r) {
                Sbuf[p][r][2 * lane]     = live ? rr[r][0] : 0.0;
                Sbuf[p][r][2 * lane + 1] = live ? rr[r][1] : 0.0;
            }
        }
    };

    // ---- load my rows into registers ----
#pragma unroll
    for (int u = 0; u < 6; ++u) {
        if (lane < 48) {
            rr[u][0] = As[(6 * wave + u) * LD + 2 * lane];
            rr[u][1] = As[(6 * wave + u) * LD + 2 * lane + 1];
        } else { rr[u][0] = 0.0; rr[u][1] = 0.0; }
    }
    if (wave == 0) prefactor(0, 0, 1.0, 0);
    __syncthreads();

    // ---- rank-6 super-steps, matrix in registers ----
    int j = 0, s = 0;
    for (; j + 6 <= n - 1; j += 6, ++s) {
        const int par = s & 1;
        if (tid >= j && tid < j + 6) {           // emission (precomputed)
            int q = tid - j;
            if ((evmask[par] >> q) & 1) myprob = ev[par][q];
        }
        if (sdead[par]) break;
        const bool nexts = (j + 12 <= n - 1);    // next super-step exists

        if (wave >= s + 1 && lane < 48) {
            double S0[6], S1[6];
#pragma unroll
            for (int r = 0; r < 6; ++r) {
                double2 sv = *(const double2*)&Sbuf[par][r][2 * lane];
                S0[r] = sv.x; S1[r] = sv.y;
            }
            // a-values = my wave's own frozen panel cols (j..j+5), held by
            // lanes 3s..3s+2: wave-uniform readlane, SGPR operands.
#pragma unroll
            for (int u = 0; u < 6; ++u) {
#pragma unroll
                for (int r = 0; r < 6; ++r) {
                    double a = rdlane(rr[u][r & 1], 3 * s + (r >> 1));
                    rr[u][0] -= a * S0[r];
                    rr[u][1] -= a * S1[r];
                }
            }
        }
        // owner of step s+1: own-rows update above, then in-place GJ.
        if (nexts && wave == s + 1)
            prefactor(j + 6, par ^ 1, gs_runprod, gs_dead);
        __syncthreads();
    }

    // ---- mini-LU tail: static shuffle-GJ with predicated guards ----
    const int  jend = j;
    const bool full = (jend + 6 > n - 1);        // loop completed (no dead-break)
    if (full && wave == (jend / 6)) {
        const int rsz = n - jend;                // 1..6
        const int jeH = jend >> 1;               // jend even (multiple of 6)
        double grun = gs_runprod; int gdead = gs_dead;
        int msk = 0;
#pragma unroll
        for (int cc = 0; cc < 6; ++cc) {
            const int src = jeH + (cc >> 1);
            double piv = rdlane(rr[cc][cc & 1], src);
            double evv = 0.0;
            if (cc < rsz - 1) {                  // interior pivot
                if (!gdead) {
                    double ap = fabs(piv);
                    int jj = jend + cc;
                    if (jj >= xmin) {
                        evv = grun * (1.0 - piv); msk |= (1 << cc);
                        double nr = grun * piv;
                        if (!(ap > 1e-7) || !(ap < 8.0) || !(fabs(nr) > 1e-8)) gdead = 1;
                        else grun = nr;
                    } else {
                        if (!(ap > 1e-12) || !(ap < 8.0)) gdead = 1;
                    }
                }
            } else if (cc == rsz - 1) {          // x = xmax-1: remaining mass
                if (!gdead) { evv = grun * (1.0 - piv); msk |= (1 << cc); }
            }
            if (lane == 0) evm[cc] = evv;
            double rp = frcp(piv);
            rr[cc][0] *= rp; rr[cc][1] *= rp;
#pragma unroll
            for (int i = 0; i < 6; ++i) {
                if (i == cc) continue;
                double f = rdlane(rr[i][cc & 1], src);
                rr[i][0] -= f * rr[cc][0];
                rr[i][1] -= f * rr[cc][1];
            }
        }
        if (lane == 0) evmmask = msk;
    }
    __syncthreads();
    if (full && tid >= jend && tid < n) {
        int q = tid - jend;
        if ((evmmask >> q) & 1) myprob = evm[q];
    }

    if (tid < Dd) {
        double p = myprob;
        if (!isfinite(p)) p = 0.0;
        if (!(fabs(p) > 1e-15)) p = 0.0;   // reference's flush
        p = fmin(fmax(p, 0.0), 1.0);       // junk-proof projection
        out[k * Dd + tid] = (float)p;
    }

    // ---- merged prob_sample: last-arriving block does the product ----
    __threadfence();
    __syncthreads();
    if (wave == 0) {
        int old = 0;
        if (lane == 0)
            old = (int)__hip_atomic_fetch_add(cnt, 1u, __ATOMIC_ACQ_REL,
                                              __HIP_MEMORY_SCOPE_AGENT);
        old = __shfl(old, 0, 64);
        // Exactly one multiple of Nn in any Nn consecutive values -> exactly
        // one trigger per launch for ANY initial/poisoned counter value.
        if (((unsigned)old + 1u) % (unsigned)Nn == 0u) {
            __threadfence();            // acquire side
            double v = 1.0;
            if (lane < Nn) {
                float f = __hip_atomic_load(out + lane * Dd + occ[lane],
                                            __ATOMIC_RELAXED, __HIP_MEMORY_SCOPE_AGENT);
                v = (double)f;
            }
#pragma unroll
            for (int off = 32; off >= 1; off >>= 1)
                v *= __shfl_down(v, off, 64);
            if (lane == 0) {
                if (!isfinite(v)) v = 0.0;
                out[Nn * Dd] = (float)v;
            }
        }
    }
}

extern "C" void kernel_launch(void* const* d_in, const int* in_sizes, int n_in,
                              void* d_out, int out_size, void* d_ws, size_t ws_size,
                              hipStream_t stream) {
    const float* P = (const float*)d_in[0];      // 96x48 f32, row-major
    const int* occ = (const int*)d_in[1];        // 48 int32
    float* out = (float*)d_out;                  // 4609 f32

    slater_kernel<<<Nn, 1024, 0, stream>>>(P, occ, out, (unsigned*)d_ws);
}

// Round 8
// 96.034 us; speedup vs baseline: 1.1485x; 1.0177x over previous
//
#include <hip/hip_runtime.h>
#include <math.h>

#define Dd 96
#define Nn 48
#define LD 97
#define PTS 98   // even stride: keeps float2 (8 B) LDS loads aligned

// Fast full-precision f64 reciprocal: v_rcp_f64 + 2 Newton steps (<=1 ulp).
__device__ __forceinline__ double frcp(double x) {
    double r = __builtin_amdgcn_rcp(x);
    r = fma(fma(-x, r, 1.0), r, r);
    r = fma(fma(-x, r, 1.0), r, r);
    return r;
}

// Wave-uniform f64 broadcast from a lane (v_readlane -> SGPR pair, no LDS).
__device__ __forceinline__ double rdlane(double v, int srcLane) {
    union { double d; int i[2]; } u; u.d = v;
    int lo = __builtin_amdgcn_readlane(u.i[0], srcLane);
    int hi = __builtin_amdgcn_readlane(u.i[1], srcLane);
    union { int i[2]; double d; } w; w.i[0] = lo; w.i[1] = hi;
    return w.d;
}

// One block per particle k (P f32; R16-verified math).
// R27: async producer-consumer pipeline (no main-loop __syncthreads).
//  - R26 diagnosis: ~2000 cy/step of barrier convoy (15 waves idle while the
//    owner runs its serial GJ; then barrier + re-entry latency). Only real
//    cross-wave dependency is Sbuf[s] from wave s -> replace the barrier with
//    step_pub publish/subscribe (acquire/release LDS atomics + s_sleep).
//    Critical path becomes the owner chain only (~1200 cy/step).
//  - Sbuf depth 4; slot reuse guarded by monotonic done[] counters:
//    consumers of step s (waves s+1..15, exactly 15-s) add after their
//    S-loads retire; owner(p>=4) waits done[p&3] >= T(p),
//    T = m*(15-q)-2m(m-1), m=p>>2, q=p&3 (cumulative closed form).
//  - Dead handling: all waves break at the first sdead16[s]; no publish
//    beyond it is ever awaited (owner s+1 breaks before prefactoring).
//  - Emissions: full ev16/evmask16 arrays (zero-init), collected after one
//    final __syncthreads; tail mini-LU as R26. FP sequence identical to R26.
__global__ __launch_bounds__(1024, 1) void slater_kernel(const float* __restrict__ P,
                                                         const int* __restrict__ occ,
                                                         float* __restrict__ out,
                                                         unsigned* __restrict__ cnt) {
    __shared__ double As[Dd * LD];      // 74,496 B (build + initial reg load)
    __shared__ double Sbuf[4][6][Dd];   // 18,432 B: S rows, 4-deep pipeline
    __shared__ double ev16[16][6];      // per-panel emissions (no reuse)
    __shared__ int    evmask16[16], sdead16[16];
    __shared__ double evm[6];           // mini-LU emissions
    __shared__ int    evmmask;
    __shared__ double gs_runprod;       // guard-state chain (owner-serialized)
    __shared__ int    gs_dead;
    __shared__ int    step_pub;         // highest published step (monotonic)
    __shared__ int    done4[4];         // per-slot consumption counters (monotonic)
    __shared__ unsigned char flag[Dd];
    float* PT = (float*)As;             // scratch alias; PT reads end before As writes

    const int tid  = threadIdx.x;
    const int k    = blockIdx.x;
    const int n    = Dd - Nn + k + 1;   // xmax
    const int lane = tid & 63;
    const int wave = tid >> 6;          // 0..15
    const int xmin = (k == 0) ? 0 : occ[k - 1] + 1;
    const int s_end = (n - 1) / 6;      // number of full rank-6 steps (8..15)
    const int jend  = 6 * s_end;

    if (tid == 0) { step_pub = -1; gs_runprod = 1.0; gs_dead = 0; evmmask = 0; }
    if (tid < 4)  done4[tid] = 0;
    if (tid < 16) { evmask16[tid] = 0; sdead16[tid] = 0; }
    if (tid < Dd) flag[tid] = 0;
    __syncthreads();
    if (tid < k) flag[occ[tid]] = 1;
    for (int e = tid; e < Dd * Nn; e += 1024) {      // PT[t][c] = P[c][t]
        int c = e / Nn, t = e - (e / Nn) * Nn;
        PT[t * PTS + c] = P[e];
    }
    __syncthreads();

    // A = I*(1-flag) - P P^T is SYMMETRIC: upper-tri 2x2 tiles (1176), mirror
    // writes for the lower half. 1024 threads -> 2 partial iterations.
    double Areg[8]; int trs[2], tcs[2];
#pragma unroll
    for (int it = 0; it < 2; ++it) {
        int tau = tid + 1024 * it;
        double s00 = 0.0, s01 = 0.0, s10 = 0.0, s11 = 0.0;
        int tr = 0, tc = 0;
        if (tau < 1176) {
            tr = (int)((97.0 - sqrt(9409.0 - 8.0 * (double)tau)) * 0.5);
            while ((tr * (97 - tr)) / 2 > tau) --tr;            // off(tr) <= tau
            while (((tr + 1) * (96 - tr)) / 2 <= tau) ++tr;     // off(tr+1) > tau
            tc = tr + (tau - (tr * (97 - tr)) / 2);
            int r0 = 2 * tr, c0 = 2 * tc;
            if (r0 < n && c0 < n) {
                for (int t = 0; t < Nn; ++t) {
                    const float* row = PT + t * PTS;
                    float2 pr = *(const float2*)(row + r0);
                    float2 pc = *(const float2*)(row + c0);
                    s00 -= (double)pr.x * (double)pc.x; s01 -= (double)pr.x * (double)pc.y;
                    s10 -= (double)pr.y * (double)pc.x; s11 -= (double)pr.y * (double)pc.y;
                }
            }
        }
        trs[it] = tr; tcs[it] = tc;
        Areg[it * 4 + 0] = s00; Areg[it * 4 + 1] = s01;
        Areg[it * 4 + 2] = s10; Areg[it * 4 + 3] = s11;
    }
    __syncthreads();                    // all PT reads done before As overwrite
#pragma unroll
    for (int it = 0; it < 2; ++it) {
        int tau = tid + 1024 * it;
        if (tau < 1176) {
            int tr = trs[it], tc = tcs[it];
            int r0 = 2 * tr, c0 = 2 * tc;
            if (r0 < n && c0 < n) {
                bool r1 = (r0 + 1 < n), c1 = (c0 + 1 < n);
                double d0 = flag[r0] ? 0.0 : 1.0;
                double d1 = flag[r0 + 1] ? 0.0 : 1.0;
                As[r0 * LD + c0] = Areg[it * 4 + 0] + ((r0 == c0) ? d0 : 0.0);
                if (c1)       As[r0 * LD + c0 + 1]       = Areg[it * 4 + 1];
                if (r1)       As[(r0 + 1) * LD + c0]     = Areg[it * 4 + 2];
                if (r1 && c1) As[(r0 + 1) * LD + c0 + 1] = Areg[it * 4 + 3] + ((r0 == c0) ? d1 : 0.0);
                if (tr != tc) {  // mirror (transpose) write
                    As[c0 * LD + r0] = Areg[it * 4 + 0];
                    if (c1)       As[(c0 + 1) * LD + r0]     = Areg[it * 4 + 1];
                    if (r1)       As[c0 * LD + r0 + 1]       = Areg[it * 4 + 2];
                    if (r1 && c1) As[(c0 + 1) * LD + r0 + 1] = Areg[it * 4 + 3];
                }
            }
        }
    }
    __syncthreads();

    double myprob = 0.0;
    double rr[6][2];                    // my 6 rows x my 2 cols

    // ---- load my rows into registers ----
#pragma unroll
    for (int u = 0; u < 6; ++u) {
        if (lane < 48) {
            rr[u][0] = As[(6 * wave + u) * LD + 2 * lane];
            rr[u][1] = As[(6 * wave + u) * LD + 2 * lane + 1];
        } else { rr[u][0] = 0.0; rr[u][1] = 0.0; }
    }

    // Owner-wave shuffle-GJ (in place: rr -> S = B^-1 R), guard chain,
    // emission/gs writes, Sbuf publish + release-store of step_pub.
    auto prefactor = [&](int p, int slot) {
        const int jb = 6 * p, jbH = 3 * p;
        double grun = gs_runprod; int gdead = gs_dead;   // ordered by prior acquire
        int msk = 0;
#pragma unroll
        for (int cc = 0; cc < 6; ++cc) {
            const int src = jbH + (cc >> 1);
            double piv = rdlane(rr[cc][cc & 1], src);
            if (!gdead) {
                double ap = fabs(piv);
                int jj = jb + cc;
                if (jj >= xmin) {
                    if (lane == 0) ev16[p][cc] = grun * (1.0 - piv);  // emit BEFORE cut
                    msk |= (1 << cc);
                    double nr = grun * piv;
                    if (!(ap > 1e-7) || !(ap < 8.0) || !(fabs(nr) > 1e-8)) gdead = 1;
                    else grun = nr;
                } else {
                    if (!(ap > 1e-12) || !(ap < 8.0)) gdead = 1;
                }
            }
            double rp = frcp(piv);
            rr[cc][0] *= rp; rr[cc][1] *= rp;
#pragma unroll
            for (int i = 0; i < 6; ++i) {
                if (i == cc) continue;
                double f = rdlane(rr[i][cc & 1], src);
                rr[i][0] -= f * rr[cc][0];
                rr[i][1] -= f * rr[cc][1];
            }
        }
        if (lane == 0) {
            evmask16[p] = msk; sdead16[p] = gdead;
            gs_runprod = grun; gs_dead = gdead;
        }
        if (lane < 48) {
            const bool live = (2 * lane >= jb + 6);
#pragma unroll
            for (int r = 0; r < 6; ++r) {
                double2 sv;
                sv.x = live ? rr[r][0] : 0.0;
                sv.y = live ? rr[r][1] : 0.0;
                *(double2*)&Sbuf[slot][r][2 * lane] = sv;
            }
        }
        __threadfence_block();
        if (lane == 0)
            __hip_atomic_store(&step_pub, p, __ATOMIC_RELEASE, __HIP_MEMORY_SCOPE_WORKGROUP);
    };

    if (wave == 0) prefactor(0, 0);     // seed the pipeline

    // ---- async rank-6 pipeline: wave w participates in steps 0..min(w,s_end)-1 ----
    bool broke = false;
    const int smax = (wave < s_end) ? wave : s_end;
    for (int s = 0; s < smax; ++s) {
        while (__hip_atomic_load(&step_pub, __ATOMIC_ACQUIRE,
                                 __HIP_MEMORY_SCOPE_WORKGROUP) < s)
            __builtin_amdgcn_s_sleep(1);
        if (sdead16[s]) { broke = true; break; }
        const int slot = s & 3;
        double S0[6], S1[6];
        if (lane < 48) {
#pragma unroll
            for (int r = 0; r < 6; ++r) {
                double2 sv = *(const double2*)&Sbuf[slot][r][2 * lane];
                S0[r] = sv.x; S1[r] = sv.y;
            }
        }
        asm volatile("s_waitcnt lgkmcnt(0)" ::: "memory");   // S-loads retired
        if (lane == 0)
            __hip_atomic_fetch_add(&done4[slot], 1, __ATOMIC_RELAXED,
                                   __HIP_MEMORY_SCOPE_WORKGROUP);
        if (lane < 48) {
            const int al = 3 * s;       // lanes holding frozen panel cols j..j+5
#pragma unroll
            for (int u = 0; u < 6; ++u) {
#pragma unroll
                for (int r = 0; r < 6; ++r) {
                    double a = rdlane(rr[u][r & 1], al + (r >> 1));
                    rr[u][0] -= a * S0[r];
                    rr[u][1] -= a * S1[r];
                }
            }
        }
        if (wave == s + 1 && s + 1 < s_end) {    // I'm the next owner
            const int p = s + 1;
            if (p >= 4) {                        // slot-reuse guard
                const int q = p & 3, m = p >> 2;
                const int T = m * (15 - q) - 2 * m * (m - 1);
                while (__hip_atomic_load(&done4[q], __ATOMIC_ACQUIRE,
                                         __HIP_MEMORY_SCOPE_WORKGROUP) < T)
                    __builtin_amdgcn_s_sleep(1);
            }
            prefactor(p, p & 3);
        }
    }

    // ---- tail mini-LU (rows jend..n-1 live in wave s_end's registers) ----
    if (!broke && wave == s_end) {
        const int rsz = n - jend;                // 1..6
        double grun = gs_runprod; int gdead = gs_dead;   // ordered by last spin
        int msk = 0;
#pragma unroll
        for (int cc = 0; cc < 6; ++cc) {
            const int src = 3 * s_end + (cc >> 1);
            double piv = rdlane(rr[cc][cc & 1], src);
            double evv = 0.0;
            if (cc < rsz - 1) {                  // interior pivot
                if (!gdead) {
                    double ap = fabs(piv);
                    int jj = jend + cc;
                    if (jj >= xmin) {
                        evv = grun * (1.0 - piv); msk |= (1 << cc);
                        double nr = grun * piv;
                        if (!(ap > 1e-7) || !(ap < 8.0) || !(fabs(nr) > 1e-8)) gdead = 1;
                        else grun = nr;
                    } else {
                        if (!(ap > 1e-12) || !(ap < 8.0)) gdead = 1;
                    }
                }
            } else if (cc == rsz - 1) {          // x = xmax-1: remaining mass
                if (!gdead) { evv = grun * (1.0 - piv); msk |= (1 << cc); }
            }
            if (lane == 0) evm[cc] = evv;
            double rp = frcp(piv);
            rr[cc][0] *= rp; rr[cc][1] *= rp;
#pragma unroll
            for (int i = 0; i < 6; ++i) {
                if (i == cc) continue;
                double f = rdlane(rr[i][cc & 1], src);
                rr[i][0] -= f * rr[cc][0];
                rr[i][1] -= f * rr[cc][1];
            }
        }
        if (lane == 0) evmmask = msk;
    }
    __syncthreads();                    // ONE barrier: everything published

    // ---- collect emissions ----
    if (tid < jend) {
        int sp = tid / 6, q = tid - 6 * sp;
        if ((evmask16[sp] >> q) & 1) myprob = ev16[sp][q];
    } else if (tid < n) {
        int q = tid - jend;
        if ((evmmask >> q) & 1) myprob = evm[q];
    }

    if (tid < Dd) {
        double p = myprob;
        if (!isfinite(p)) p = 0.0;
        if (!(fabs(p) > 1e-15)) p = 0.0;   // reference's flush
        p = fmin(fmax(p, 0.0), 1.0);       // junk-proof projection
        out[k * Dd + tid] = (float)p;
    }

    // ---- merged prob_sample: last-arriving block does the product ----
    __threadfence();
    __syncthreads();
    if (wave == 0) {
        int old = 0;
        if (lane == 0)
            old = (int)__hip_atomic_fetch_add(cnt, 1u, __ATOMIC_ACQ_REL,
                                              __HIP_MEMORY_SCOPE_AGENT);
        old = __shfl(old, 0, 64);
        // Exactly one multiple of Nn in any Nn consecutive values -> exactly
        // one trigger per launch for ANY initial/poisoned counter value.
        if (((unsigned)old + 1u) % (unsigned)Nn == 0u) {
            __threadfence();            // acquire side
            double v = 1.0;
            if (lane < Nn) {
                float f = __hip_atomic_load(out + lane * Dd + occ[lane],
                                            __ATOMIC_RELAXED, __HIP_MEMORY_SCOPE_AGENT);
                v = (double)f;
            }
#pragma unroll
            for (int off = 32; off >= 1; off >>= 1)
                v *= __shfl_down(v, off, 64);
            if (lane == 0) {
                if (!isfinite(v)) v = 0.0;
                out[Nn * Dd] = (float)v;
            }
        }
    }
}

extern "C" void kernel_launch(void* const* d_in, const int* in_sizes, int n_in,
                              void* d_out, int out_size, void* d_ws, size_t ws_size,
                              hipStream_t stream) {
    const float* P = (const float*)d_in[0];      // 96x48 f32, row-major
    const int* occ = (const int*)d_in[1];        // 48 int32
    float* out = (float*)d_out;                  // 4609 f32

    slater_kernel<<<Nn, 1024, 0, stream>>>(P, occ, out, (unsigned*)d_ws);
}

// Round 9
// 93.643 us; speedup vs baseline: 1.1778x; 1.0255x over previous
//
#include <hip/hip_runtime.h>
#include <math.h>

#define Dd 96
#define Nn 48
#define LD 97
#define PTS 98   // even stride (mono fallback only)
#define WS_G_BYTES (Dd * Dd * 8)   // 73,728 B for shared G matrix

// Fast full-precision f64 reciprocal: v_rcp_f64 + 2 Newton steps (<=1 ulp).
__device__ __forceinline__ double frcp(double x) {
    double r = __builtin_amdgcn_rcp(x);
    r = fma(fma(-x, r, 1.0), r, r);
    r = fma(fma(-x, r, 1.0), r, r);
    return r;
}

// Wave-uniform f64 broadcast from a lane (v_readlane -> SGPR pair, no LDS).
__device__ __forceinline__ double rdlane(double v, int srcLane) {
    union { double d; int i[2]; } u; u.d = v;
    int lo = __builtin_amdgcn_readlane(u.i[0], srcLane);
    int hi = __builtin_amdgcn_readlane(u.i[1], srcLane);
    union { int i[2]; double d; } w; w.i[0] = lo; w.i[1] = hi;
    return w.d;
}

// ============================================================================
// R28 K1: G-matrix build, ONCE for all blocks. M[r][c] = -sum_t P[r][t]P[c][t]
// (same FP op order as the per-block builds: acc starts 0.0, subtract in
// ascending t). Diagonal/flag terms are added at load time in K2.
// ============================================================================
__global__ __launch_bounds__(256) void build_g(const float* __restrict__ P,
                                               double* __restrict__ Mg) {
    __shared__ float Ps[Dd * 48];       // 18,432 B
    const int t0 = threadIdx.x;
    for (int e = t0; e < Dd * 48; e += 256) Ps[e] = P[e];
    __syncthreads();
    const int e = blockIdx.x * 256 + t0;     // 0..9215
    const int r = e / Dd, c = e - Dd * (e / Dd);
    const float* pr = Ps + r * 48;
    const float* pc = Ps + c * 48;
    double acc = 0.0;
#pragma unroll
    for (int t = 0; t < 48; ++t)
        acc -= (double)pr[t] * (double)pc[t];
    Mg[e] = acc;
}

// ============================================================================
// R28 K2: R27's async producer-consumer elimination, with the A-build phase
// DELETED (rr loads straight from Mg; diag+flag added at load, FP-identical).
// LDS drops 94 KB -> ~20 KB. Everything else verbatim from R27.
// ============================================================================
__global__ __launch_bounds__(1024, 1) void slater_elim(const double* __restrict__ Mg,
                                                       const int* __restrict__ occ,
                                                       float* __restrict__ out,
                                                       unsigned* __restrict__ cnt) {
    __shared__ double Sbuf[4][6][Dd];   // 18,432 B: S rows, 4-deep pipeline
    __shared__ double ev16[16][6];      // per-panel emissions
    __shared__ int    evmask16[16], sdead16[16];
    __shared__ double evm[6];           // mini-LU emissions
    __shared__ int    evmmask;
    __shared__ double gs_runprod;       // guard-state chain (owner-serialized)
    __shared__ int    gs_dead;
    __shared__ int    step_pub;         // highest published step (monotonic)
    __shared__ int    done4[4];         // per-slot consumption counters
    __shared__ unsigned char flag[Dd];

    const int tid  = threadIdx.x;
    const int k    = blockIdx.x;
    const int n    = Dd - Nn + k + 1;   // xmax
    const int lane = tid & 63;
    const int wave = tid >> 6;          // 0..15
    const int xmin = (k == 0) ? 0 : occ[k - 1] + 1;
    const int s_end = (n - 1) / 6;      // number of full rank-6 steps (8..15)
    const int jend  = 6 * s_end;

    if (tid == 0) { step_pub = -1; gs_runprod = 1.0; gs_dead = 0; evmmask = 0; }
    if (tid < 4)  done4[tid] = 0;
    if (tid < 16) { evmask16[tid] = 0; sdead16[tid] = 0; }
    if (tid < Dd) flag[tid] = 0;
    __syncthreads();
    if (tid < k) flag[occ[tid]] = 1;
    __syncthreads();                    // flags ready before rr load

    double myprob = 0.0;
    double rr[6][2];                    // my 6 rows x my 2 cols

    // ---- load my rows from the shared G (global, L2-broadcast) ----
#pragma unroll
    for (int u = 0; u < 6; ++u) {
        if (lane < 48) {
            const int row = 6 * wave + u;
            double2 g = *(const double2*)(Mg + row * Dd + 2 * lane);
            double d0 = (row == 2 * lane     && !flag[row]) ? 1.0 : 0.0;
            double d1 = (row == 2 * lane + 1 && !flag[row]) ? 1.0 : 0.0;
            rr[u][0] = g.x + d0;
            rr[u][1] = g.y + d1;
        } else { rr[u][0] = 0.0; rr[u][1] = 0.0; }
    }

    // Owner-wave shuffle-GJ (in place: rr -> S = B^-1 R), guard chain,
    // emission/gs writes, Sbuf publish + release-store of step_pub.
    auto prefactor = [&](int p, int slot) {
        const int jb = 6 * p, jbH = 3 * p;
        double grun = gs_runprod; int gdead = gs_dead;
        int msk = 0;
#pragma unroll
        for (int cc = 0; cc < 6; ++cc) {
            const int src = jbH + (cc >> 1);
            double piv = rdlane(rr[cc][cc & 1], src);
            if (!gdead) {
                double ap = fabs(piv);
                int jj = jb + cc;
                if (jj >= xmin) {
                    if (lane == 0) ev16[p][cc] = grun * (1.0 - piv);  // emit BEFORE cut
                    msk |= (1 << cc);
                    double nr = grun * piv;
                    if (!(ap > 1e-7) || !(ap < 8.0) || !(fabs(nr) > 1e-8)) gdead = 1;
                    else grun = nr;
                } else {
                    if (!(ap > 1e-12) || !(ap < 8.0)) gdead = 1;
                }
            }
            double rp = frcp(piv);
            rr[cc][0] *= rp; rr[cc][1] *= rp;
#pragma unroll
            for (int i = 0; i < 6; ++i) {
                if (i == cc) continue;
                double f = rdlane(rr[i][cc & 1], src);
                rr[i][0] -= f * rr[cc][0];
                rr[i][1] -= f * rr[cc][1];
            }
        }
        if (lane == 0) {
            evmask16[p] = msk; sdead16[p] = gdead;
            gs_runprod = grun; gs_dead = gdead;
        }
        if (lane < 48) {
            const bool live = (2 * lane >= jb + 6);
#pragma unroll
            for (int r = 0; r < 6; ++r) {
                double2 sv;
                sv.x = live ? rr[r][0] : 0.0;
                sv.y = live ? rr[r][1] : 0.0;
                *(double2*)&Sbuf[slot][r][2 * lane] = sv;
            }
        }
        __threadfence_block();
        if (lane == 0)
            __hip_atomic_store(&step_pub, p, __ATOMIC_RELEASE, __HIP_MEMORY_SCOPE_WORKGROUP);
    };

    if (wave == 0) prefactor(0, 0);     // seed the pipeline

    // ---- async rank-6 pipeline: wave w participates in steps 0..min(w,s_end)-1 ----
    bool broke = false;
    const int smax = (wave < s_end) ? wave : s_end;
    for (int s = 0; s < smax; ++s) {
        while (__hip_atomic_load(&step_pub, __ATOMIC_ACQUIRE,
                                 __HIP_MEMORY_SCOPE_WORKGROUP) < s)
            __builtin_amdgcn_s_sleep(1);
        if (sdead16[s]) { broke = true; break; }
        const int slot = s & 3;
        double S0[6], S1[6];
        if (lane < 48) {
#pragma unroll
            for (int r = 0; r < 6; ++r) {
                double2 sv = *(const double2*)&Sbuf[slot][r][2 * lane];
                S0[r] = sv.x; S1[r] = sv.y;
            }
        }
        asm volatile("s_waitcnt lgkmcnt(0)" ::: "memory");   // S-loads retired
        if (lane == 0)
            __hip_atomic_fetch_add(&done4[slot], 1, __ATOMIC_RELAXED,
                                   __HIP_MEMORY_SCOPE_WORKGROUP);
        if (lane < 48) {
            const int al = 3 * s;       // lanes holding frozen panel cols j..j+5
#pragma unroll
            for (int u = 0; u < 6; ++u) {
#pragma unroll
                for (int r = 0; r < 6; ++r) {
                    double a = rdlane(rr[u][r & 1], al + (r >> 1));
                    rr[u][0] -= a * S0[r];
                    rr[u][1] -= a * S1[r];
                }
            }
        }
        if (wave == s + 1 && s + 1 < s_end) {    // I'm the next owner
            const int p = s + 1;
            if (p >= 4) {                        // slot-reuse guard
                const int q = p & 3, m = p >> 2;
                const int T = m * (15 - q) - 2 * m * (m - 1);
                while (__hip_atomic_load(&done4[q], __ATOMIC_ACQUIRE,
                                         __HIP_MEMORY_SCOPE_WORKGROUP) < T)
                    __builtin_amdgcn_s_sleep(1);
            }
            prefactor(p, p & 3);
        }
    }

    // ---- tail mini-LU (rows jend..n-1 live in wave s_end's registers) ----
    if (!broke && wave == s_end) {
        const int rsz = n - jend;                // 1..6
        double grun = gs_runprod; int gdead = gs_dead;
        int msk = 0;
#pragma unroll
        for (int cc = 0; cc < 6; ++cc) {
            const int src = 3 * s_end + (cc >> 1);
            double piv = rdlane(rr[cc][cc & 1], src);
            double evv = 0.0;
            if (cc < rsz - 1) {                  // interior pivot
                if (!gdead) {
                    double ap = fabs(piv);
                    int jj = jend + cc;
                    if (jj >= xmin) {
                        evv = grun * (1.0 - piv); msk |= (1 << cc);
                        double nr = grun * piv;
                        if (!(ap > 1e-7) || !(ap < 8.0) || !(fabs(nr) > 1e-8)) gdead = 1;
                        else grun = nr;
                    } else {
                        if (!(ap > 1e-12) || !(ap < 8.0)) gdead = 1;
                    }
                }
            } else if (cc == rsz - 1) {          // x = xmax-1: remaining mass
                if (!gdead) { evv = grun * (1.0 - piv); msk |= (1 << cc); }
            }
            if (lane == 0) evm[cc] = evv;
            double rp = frcp(piv);
            rr[cc][0] *= rp; rr[cc][1] *= rp;
#pragma unroll
            for (int i = 0; i < 6; ++i) {
                if (i == cc) continue;
                double f = rdlane(rr[i][cc & 1], src);
                rr[i][0] -= f * rr[cc][0];
                rr[i][1] -= f * rr[cc][1];
            }
        }
        if (lane == 0) evmmask = msk;
    }
    __syncthreads();                    // ONE barrier: everything published

    // ---- collect emissions ----
    if (tid < jend) {
        int sp = tid / 6, q = tid - 6 * sp;
        if ((evmask16[sp] >> q) & 1) myprob = ev16[sp][q];
    } else if (tid < n) {
        int q = tid - jend;
        if ((evmmask >> q) & 1) myprob = evm[q];
    }

    if (tid < Dd) {
        double p = myprob;
        if (!isfinite(p)) p = 0.0;
        if (!(fabs(p) > 1e-15)) p = 0.0;   // reference's flush
        p = fmin(fmax(p, 0.0), 1.0);       // junk-proof projection
        out[k * Dd + tid] = (float)p;
    }

    // ---- merged prob_sample: last-arriving block does the product ----
    __threadfence();
    __syncthreads();
    if (wave == 0) {
        int old = 0;
        if (lane == 0)
            old = (int)__hip_atomic_fetch_add(cnt, 1u, __ATOMIC_ACQ_REL,
                                              __HIP_MEMORY_SCOPE_AGENT);
        old = __shfl(old, 0, 64);
        if (((unsigned)old + 1u) % (unsigned)Nn == 0u) {
            __threadfence();            // acquire side
            double v = 1.0;
            if (lane < Nn) {
                float f = __hip_atomic_load(out + lane * Dd + occ[lane],
                                            __ATOMIC_RELAXED, __HIP_MEMORY_SCOPE_AGENT);
                v = (double)f;
            }
#pragma unroll
            for (int off = 32; off >= 1; off >>= 1)
                v *= __shfl_down(v, off, 64);
            if (lane == 0) {
                if (!isfinite(v)) v = 0.0;
                out[Nn * Dd] = (float)v;
            }
        }
    }
}

// ============================================================================
// Fallback: R27 monolithic kernel, verbatim (used only if ws is too small).
// ============================================================================
__global__ __launch_bounds__(1024, 1) void slater_mono(const float* __restrict__ P,
                                                       const int* __restrict__ occ,
                                                       float* __restrict__ out,
                                                       unsigned* __restrict__ cnt) {
    __shared__ double As[Dd * LD];
    __shared__ double Sbuf[4][6][Dd];
    __shared__ double ev16[16][6];
    __shared__ int    evmask16[16], sdead16[16];
    __shared__ double evm[6];
    __shared__ int    evmmask;
    __shared__ double gs_runprod;
    __shared__ int    gs_dead;
    __shared__ int    step_pub;
    __shared__ int    done4[4];
    __shared__ unsigned char flag[Dd];
    float* PT = (float*)As;

    const int tid  = threadIdx.x;
    const int k    = blockIdx.x;
    const int n    = Dd - Nn + k + 1;
    const int lane = tid & 63;
    const int wave = tid >> 6;
    const int xmin = (k == 0) ? 0 : occ[k - 1] + 1;
    const int s_end = (n - 1) / 6;
    const int jend  = 6 * s_end;

    if (tid == 0) { step_pub = -1; gs_runprod = 1.0; gs_dead = 0; evmmask = 0; }
    if (tid < 4)  done4[tid] = 0;
    if (tid < 16) { evmask16[tid] = 0; sdead16[tid] = 0; }
    if (tid < Dd) flag[tid] = 0;
    __syncthreads();
    if (tid < k) flag[occ[tid]] = 1;
    for (int e = tid; e < Dd * Nn; e += 1024) {
        int c = e / Nn, t = e - (e / Nn) * Nn;
        PT[t * PTS + c] = P[e];
    }
    __syncthreads();

    double Areg[8]; int trs[2], tcs[2];
#pragma unroll
    for (int it = 0; it < 2; ++it) {
        int tau = tid + 1024 * it;
        double s00 = 0.0, s01 = 0.0, s10 = 0.0, s11 = 0.0;
        int tr = 0, tc = 0;
        if (tau < 1176) {
            tr = (int)((97.0 - sqrt(9409.0 - 8.0 * (double)tau)) * 0.5);
            while ((tr * (97 - tr)) / 2 > tau) --tr;
            while (((tr + 1) * (96 - tr)) / 2 <= tau) ++tr;
            tc = tr + (tau - (tr * (97 - tr)) / 2);
            int r0 = 2 * tr, c0 = 2 * tc;
            if (r0 < n && c0 < n) {
                for (int t = 0; t < Nn; ++t) {
                    const float* row = PT + t * PTS;
                    float2 pr = *(const float2*)(row + r0);
                    float2 pc = *(const float2*)(row + c0);
                    s00 -= (double)pr.x * (double)pc.x; s01 -= (double)pr.x * (double)pc.y;
                    s10 -= (double)pr.y * (double)pc.x; s11 -= (double)pr.y * (double)pc.y;
                }
            }
        }
        trs[it] = tr; tcs[it] = tc;
        Areg[it * 4 + 0] = s00; Areg[it * 4 + 1] = s01;
        Areg[it * 4 + 2] = s10; Areg[it * 4 + 3] = s11;
    }
    __syncthreads();
#pragma unroll
    for (int it = 0; it < 2; ++it) {
        int tau = tid + 1024 * it;
        if (tau < 1176) {
            int tr = trs[it], tc = tcs[it];
            int r0 = 2 * tr, c0 = 2 * tc;
            if (r0 < n && c0 < n) {
                bool r1 = (r0 + 1 < n), c1 = (c0 + 1 < n);
                double d0 = flag[r0] ? 0.0 : 1.0;
                double d1 = flag[r0 + 1] ? 0.0 : 1.0;
                As[r0 * LD + c0] = Areg[it * 4 + 0] + ((r0 == c0) ? d0 : 0.0);
                if (c1)       As[r0 * LD + c0 + 1]       = Areg[it * 4 + 1];
                if (r1)       As[(r0 + 1) * LD + c0]     = Areg[it * 4 + 2];
                if (r1 && c1) As[(r0 + 1) * LD + c0 + 1] = Areg[it * 4 + 3] + ((r0 == c0) ? d1 : 0.0);
                if (tr != tc) {
                    As[c0 * LD + r0] = Areg[it * 4 + 0];
                    if (c1)       As[(c0 + 1) * LD + r0]     = Areg[it * 4 + 1];
                    if (r1)       As[c0 * LD + r0 + 1]       = Areg[it * 4 + 2];
                    if (r1 && c1) As[(c0 + 1) * LD + r0 + 1] = Areg[it * 4 + 3];
                }
            }
        }
    }
    __syncthreads();

    double myprob = 0.0;
    double rr[6][2];
#pragma unroll
    for (int u = 0; u < 6; ++u) {
        if (lane < 48) {
            rr[u][0] = As[(6 * wave + u) * LD + 2 * lane];
            rr[u][1] = As[(6 * wave + u) * LD + 2 * lane + 1];
        } else { rr[u][0] = 0.0; rr[u][1] = 0.0; }
    }

    auto prefactor = [&](int p, int slot) {
        const int jb = 6 * p, jbH = 3 * p;
        double grun = gs_runprod; int gdead = gs_dead;
        int msk = 0;
#pragma unroll
        for (int cc = 0; cc < 6; ++cc) {
            const int src = jbH + (cc >> 1);
            double piv = rdlane(rr[cc][cc & 1], src);
            if (!gdead) {
                double ap = fabs(piv);
                int jj = jb + cc;
                if (jj >= xmin) {
                    if (lane == 0) ev16[p][cc] = grun * (1.0 - piv);
                    msk |= (1 << cc);
                    double nr = grun * piv;
                    if (!(ap > 1e-7) || !(ap < 8.0) || !(fabs(nr) > 1e-8)) gdead = 1;
                    else grun = nr;
                } else {
                    if (!(ap > 1e-12) || !(ap < 8.0)) gdead = 1;
                }
            }
            double rp = frcp(piv);
            rr[cc][0] *= rp; rr[cc][1] *= rp;
#pragma unroll
            for (int i = 0; i < 6; ++i) {
                if (i == cc) continue;
                double f = rdlane(rr[i][cc & 1], src);
                rr[i][0] -= f * rr[cc][0];
                rr[i][1] -= f * rr[cc][1];
            }
        }
        if (lane == 0) {
            evmask16[p] = msk; sdead16[p] = gdead;
            gs_runprod = grun; gs_dead = gdead;
        }
        if (lane < 48) {
            const bool live = (2 * lane >= jb + 6);
#pragma unroll
            for (int r = 0; r < 6; ++r) {
                double2 sv;
                sv.x = live ? rr[r][0] : 0.0;
                sv.y = live ? rr[r][1] : 0.0;
                *(double2*)&Sbuf[slot][r][2 * lane] = sv;
            }
        }
        __threadfence_block();
        if (lane == 0)
            __hip_atomic_store(&step_pub, p, __ATOMIC_RELEASE, __HIP_MEMORY_SCOPE_WORKGROUP);
    };

    if (wave == 0) prefactor(0, 0);

    bool broke = false;
    const int smax = (wave < s_end) ? wave : s_end;
    for (int s = 0; s < smax; ++s) {
        while (__hip_atomic_load(&step_pub, __ATOMIC_ACQUIRE,
                                 __HIP_MEMORY_SCOPE_WORKGROUP) < s)
            __builtin_amdgcn_s_sleep(1);
        if (sdead16[s]) { broke = true; break; }
        const int slot = s & 3;
        double S0[6], S1[6];
        if (lane < 48) {
#pragma unroll
            for (int r = 0; r < 6; ++r) {
                double2 sv = *(const double2*)&Sbuf[slot][r][2 * lane];
                S0[r] = sv.x; S1[r] = sv.y;
            }
        }
        asm volatile("s_waitcnt lgkmcnt(0)" ::: "memory");
        if (lane == 0)
            __hip_atomic_fetch_add(&done4[slot], 1, __ATOMIC_RELAXED,
                                   __HIP_MEMORY_SCOPE_WORKGROUP);
        if (lane < 48) {
            const int al = 3 * s;
#pragma unroll
            for (int u = 0; u < 6; ++u) {
#pragma unroll
                for (int r = 0; r < 6; ++r) {
                    double a = rdlane(rr[u][r & 1], al + (r >> 1));
                    rr[u][0] -= a * S0[r];
                    rr[u][1] -= a * S1[r];
                }
            }
        }
        if (wave == s + 1 && s + 1 < s_end) {
            const int p = s + 1;
            if (p >= 4) {
                const int q = p & 3, m = p >> 2;
                const int T = m * (15 - q) - 2 * m * (m - 1);
                while (__hip_atomic_load(&done4[q], __ATOMIC_ACQUIRE,
                                         __HIP_MEMORY_SCOPE_WORKGROUP) < T)
                    __builtin_amdgcn_s_sleep(1);
            }
            prefactor(p, p & 3);
        }
    }

    if (!broke && wave == s_end) {
        const int rsz = n - jend;
        double grun = gs_runprod; int gdead = gs_dead;
        int msk = 0;
#pragma unroll
        for (int cc = 0; cc < 6; ++cc) {
            const int src = 3 * s_end + (cc >> 1);
            double piv = rdlane(rr[cc][cc & 1], src);
            double evv = 0.0;
            if (cc < rsz - 1) {
                if (!gdead) {
                    double ap = fabs(piv);
                    int jj = jend + cc;
                    if (jj >= xmin) {
                        evv = grun * (1.0 - piv); msk |= (1 << cc);
                        double nr = grun * piv;
                        if (!(ap > 1e-7) || !(ap < 8.0) || !(fabs(nr) > 1e-8)) gdead = 1;
                        else grun = nr;
                    } else {
                        if (!(ap > 1e-12) || !(ap < 8.0)) gdead = 1;
                    }
                }
            } else if (cc == rsz - 1) {
                if (!gdead) { evv = grun * (1.0 - piv); msk |= (1 << cc); }
            }
            if (lane == 0) evm[cc] = evv;
            double rp = frcp(piv);
            rr[cc][0] *= rp; rr[cc][1] *= rp;
#pragma unroll
            for (int i = 0; i < 6; ++i) {
                if (i == cc) continue;
                double f = rdlane(rr[i][cc & 1], src);
                rr[i][0] -= f * rr[cc][0];
                rr[i][1] -= f * rr[cc][1];
            }
        }
        if (lane == 0) evmmask = msk;
    }
    __syncthreads();

    if (tid < jend) {
        int sp = tid / 6, q = tid - 6 * sp;
        if ((evmask16[sp] >> q) & 1) myprob = ev16[sp][q];
    } else if (tid < n) {
        int q = tid - jend;
        if ((evmmask >> q) & 1) myprob = evm[q];
    }

    if (tid < Dd) {
        double p = myprob;
        if (!isfinite(p)) p = 0.0;
        if (!(fabs(p) > 1e-15)) p = 0.0;
        p = fmin(fmax(p, 0.0), 1.0);
        out[k * Dd + tid] = (float)p;
    }

    __threadfence();
    __syncthreads();
    if (wave == 0) {
        int old = 0;
        if (lane == 0)
            old = (int)__hip_atomic_fetch_add(cnt, 1u, __ATOMIC_ACQ_REL,
                                              __HIP_MEMORY_SCOPE_AGENT);
        old = __shfl(old, 0, 64);
        if (((unsigned)old + 1u) % (unsigned)Nn == 0u) {
            __threadfence();
            double v = 1.0;
            if (lane < Nn) {
                float f = __hip_atomic_load(out + lane * Dd + occ[lane],
                                            __ATOMIC_RELAXED, __HIP_MEMORY_SCOPE_AGENT);
                v = (double)f;
            }
#pragma unroll
            for (int off = 32; off >= 1; off >>= 1)
                v *= __shfl_down(v, off, 64);
            if (lane == 0) {
                if (!isfinite(v)) v = 0.0;
                out[Nn * Dd] = (float)v;
            }
        }
    }
}

extern "C" void kernel_launch(void* const* d_in, const int* in_sizes, int n_in,
                              void* d_out, int out_size, void* d_ws, size_t ws_size,
                              hipStream_t stream) {
    const float* P = (const float*)d_in[0];      // 96x48 f32, row-major
    const int* occ = (const int*)d_in[1];        // 48 int32
    float* out = (float*)d_out;                  // 4609 f32

    if (ws_size >= (size_t)(WS_G_BYTES + 16)) {
        double* Mg = (double*)d_ws;
        unsigned* cnt = (unsigned*)((char*)d_ws + WS_G_BYTES);
        build_g<<<36, 256, 0, stream>>>(P, Mg);
        slater_elim<<<Nn, 1024, 0, stream>>>(Mg, occ, out, cnt);
    } else {
        slater_mono<<<Nn, 1024, 0, stream>>>(P, occ, out, (unsigned*)d_ws);
    }
}